// Round 1
// baseline (731.845 us; speedup 1.0000x reference)
//
#include <hip/hip_runtime.h>

// DenseEquivariantIrrep: B=32768, C=32, F=32, NS=48, irreps: 4x(d=1), 2x(d=2), 4x(d=3)
// y[b,f,s] = sum_j (sum_{c,r} (x[b,c,:]@fwd)[n,p,r] * (kernel[f,c,:]@fwd)[n,r,q]) * inv[j,s] + bias[f]
//
// R3: stage-C load-pipelining fix. R2 measured VGPR=84 (== 512/6: compiler
// allocated for 6 waves/EU despite waves_per_eu(3,3)), leaving ~4 float4s of
// load headroom after yh[48] -> stage C serialized into load->FMA batches with
// ~150-220cy bubbles (est. ~20% FMA efficiency, ~330us of the 425us).
// Fix: split stage C into 3 irrep-group passes (active acc <= 18 regs,
// finished slices cold) and software-pipeline each pass with explicit
// depth-2 A/B float4 register sets, forcing ~130 live VGPRs and one full
// 54-FMA block of latency hiding per load batch. FP accumulation order over
// c is unchanged per output -> results bit-identical to R2.

#define QB4 417   // float4 stride per b-row in LDS (b + 5c) mod 8 spreads bank quads
#define QC4 13    // float4 stride per c-row

// ---- prep 1: fwdT[j][t] = fwd[t][j];  invT[s][j] = fwd[s][j] * d_j/48 ----
__global__ void prep_ft(const float* __restrict__ d1, const float* __restrict__ d2,
                        const float* __restrict__ d3,
                        float* __restrict__ fwdT, float* __restrict__ invT) {
    int id = blockIdx.x * 256 + threadIdx.x;   // 0..2303
    if (id >= 48 * 48) return;
    int j = id / 48, t = id - j * 48;
    float v, scale;
    if (j < 4) {                       // d=1 irreps: [4][48][1][1]
        v = d1[j * 48 + t];
        scale = 1.0f / 48.0f;
    } else if (j < 12) {               // d=2 irreps: [2][48][2][2]
        int r = j - 4;
        int i = r >> 2, pq = r & 3;
        v = d2[i * 192 + t * 4 + pq];
        scale = 2.0f / 48.0f;
    } else {                           // d=3 irreps: [4][48][3][3]
        int r = j - 12;
        int i = r / 9, pq = r - i * 9;
        v = d3[i * 432 + t * 9 + pq];
        scale = 3.0f / 48.0f;
    }
    fwdT[j * 48 + t] = v;
    invT[t * 48 + j] = v * scale;      // transposed so stage D rows are contiguous
}

// ---- prep 2: kh[f][c][j] = sum_t kernel[f][c][t] * fwdT[j][t] ----
__global__ void prep_kh(const float* __restrict__ kern, const float* __restrict__ fwdT,
                        float* __restrict__ kh) {
    int id = blockIdx.x * 256 + threadIdx.x;   // 0..4095
    int f = id >> 7;
    int c = (id >> 2) & 31;
    int jq = id & 3;
    float kr[48];
    const float4* kp = (const float4*)(kern + (f * 32 + c) * 48);
    #pragma unroll
    for (int k = 0; k < 12; ++k) {
        float4 v = kp[k];
        kr[4*k] = v.x; kr[4*k+1] = v.y; kr[4*k+2] = v.z; kr[4*k+3] = v.w;
    }
    for (int jj = 0; jj < 12; ++jj) {
        int j = jq * 12 + jj;
        const float* fr = fwdT + j * 48;
        float acc = 0.0f;
        #pragma unroll
        for (int t = 0; t < 48; ++t) acc = fmaf(kr[t], fr[t], acc);
        kh[(f * 32 + c) * 48 + j] = acc;
    }
}

// ---- stage C helper macros ----
// UNPACK*: pure register renames after SROA (no v_mov expected).
#define UNPACK5(X, xs) \
    float xs[20]; \
    { xs[0]=X[0].x;  xs[1]=X[0].y;  xs[2]=X[0].z;  xs[3]=X[0].w;  \
      xs[4]=X[1].x;  xs[5]=X[1].y;  xs[6]=X[1].z;  xs[7]=X[1].w;  \
      xs[8]=X[2].x;  xs[9]=X[2].y;  xs[10]=X[2].z; xs[11]=X[2].w; \
      xs[12]=X[3].x; xs[13]=X[3].y; xs[14]=X[3].z; xs[15]=X[3].w; \
      xs[16]=X[4].x; xs[17]=X[4].y; xs[18]=X[4].z; xs[19]=X[4].w; }

#define UNPACK3(X, xs) \
    float xs[12]; \
    { xs[0]=X[0].x; xs[1]=X[0].y; xs[2]=X[0].z; xs[3]=X[0].w; \
      xs[4]=X[1].x; xs[5]=X[1].y; xs[6]=X[1].z; xs[7]=X[1].w; \
      xs[8]=X[2].x; xs[9]=X[2].y; xs[10]=X[2].z; xs[11]=X[2].w; }

// two d=3 irreps: 54 FMA. XO0/XO1 = float offset of each irrep within the
// 20-float window; YB0/YB1 = yh base index of each irrep's 3x3 block.
#define D3PAIR(X, K, XO0, XO1, YB0, YB1) do { \
    UNPACK5(X, _xs); UNPACK5(K, _ks); \
    _Pragma("unroll") \
    for (int p = 0; p < 3; ++p) { \
      _Pragma("unroll") \
      for (int q = 0; q < 3; ++q) { \
        float s0 = yh[YB0 + 3*p + q]; \
        s0 = fmaf(_xs[XO0 + 3*p + 0], _ks[XO0 + 0 + q], s0); \
        s0 = fmaf(_xs[XO0 + 3*p + 1], _ks[XO0 + 3 + q], s0); \
        s0 = fmaf(_xs[XO0 + 3*p + 2], _ks[XO0 + 6 + q], s0); \
        yh[YB0 + 3*p + q] = s0; \
        float s1 = yh[YB1 + 3*p + q]; \
        s1 = fmaf(_xs[XO1 + 3*p + 0], _ks[XO1 + 0 + q], s1); \
        s1 = fmaf(_xs[XO1 + 3*p + 1], _ks[XO1 + 3 + q], s1); \
        s1 = fmaf(_xs[XO1 + 3*p + 2], _ks[XO1 + 6 + q], s1); \
        yh[YB1 + 3*p + q] = s1; \
      } \
    } \
} while (0)

// d=1 (4) + d=2 (2x) irreps: 20 FMA on floats 0..11
#define D12FMA(X, K) do { \
    UNPACK3(X, _xs); UNPACK3(K, _ks); \
    _Pragma("unroll") \
    for (int n = 0; n < 4; ++n) yh[n] = fmaf(_xs[n], _ks[n], yh[n]); \
    _Pragma("unroll") \
    for (int n = 0; n < 2; ++n) { \
      const int o = 4 + 4*n; \
      _Pragma("unroll") \
      for (int p = 0; p < 2; ++p) { \
        _Pragma("unroll") \
        for (int q = 0; q < 2; ++q) { \
          float s = yh[o + 2*p + q]; \
          s = fmaf(_xs[o + 2*p + 0], _ks[o + 0 + q], s); \
          s = fmaf(_xs[o + 2*p + 1], _ks[o + 2 + q], s); \
          yh[o + 2*p + q] = s; \
        } \
      } \
    } \
} while (0)

// ---- fused main: block = 8 b-rows x 32 f ----
__global__ __launch_bounds__(256) __attribute__((amdgpu_waves_per_eu(3, 3)))
void fused_main(
    const float* __restrict__ x,
    const float* __restrict__ fwdT,
    const float* __restrict__ invT,
    const float* __restrict__ kh,
    const float* __restrict__ bias,
    float* __restrict__ out) {
    __shared__ float4 lds[8 * QB4];   // 53,376 B -> 3 blocks/CU
    const int tid = threadIdx.x;
    const long long b0 = (long long)blockIdx.x * 8;

    // ---- Stage A: coalesced load of x tile [8][32][48] into LDS (padded) ----
    const float4* xg = (const float4*)x + b0 * 384;   // 384 float4 per b-row
    #pragma unroll
    for (int it = 0; it < 12; ++it) {
        int v = tid + it * 256;          // 0..3071
        int b = v / 384;
        int w = v - b * 384;             // float4 idx within row
        int c = w / 12;
        int t4 = w - c * 12;
        lds[b * QB4 + c * QC4 + t4] = xg[v];
    }
    __syncthreads();

    // ---- Stage B: xh[b][c][:] = x[b][c][:] @ fwd  (in-place, thread = (b,c)) ----
    {
        const int b = tid >> 5, c = tid & 31;
        float4* row = &lds[b * QB4 + c * QC4];
        float xr[48];
        #pragma unroll
        for (int k = 0; k < 12; ++k) {
            float4 v = row[k];
            xr[4*k] = v.x; xr[4*k+1] = v.y; xr[4*k+2] = v.z; xr[4*k+3] = v.w;
        }
        for (int jc = 0; jc < 12; ++jc) {      // rolled: live = xr[48] + h[4]
            float h[4];
            #pragma unroll
            for (int u = 0; u < 4; ++u) {
                const float* fr = fwdT + (jc * 4 + u) * 48;   // uniform -> s_load
                float acc = 0.0f;
                #pragma unroll
                for (int t = 0; t < 48; ++t) acc = fmaf(xr[t], fr[t], acc);
                h[u] = acc;
            }
            row[jc] = make_float4(h[0], h[1], h[2], h[3]);
        }
    }
    __syncthreads();

    // ---- Stage C: yh[j] = sum_{c,r} xh * kh   (thread = (b,f)) ----
    // 3 irrep-group passes over c, each depth-2 software-pipelined (A/B sets).
    {
        const int b = tid & 7, f = tid >> 3;
        float yh[48];

        const float4* khp = (const float4*)kh + f * 384;   // kh[f][c][48], 12 f4/row
        const float4* xrow0 = &lds[b * QB4];               // xh[b][c][48], 13 f4/row

        // -- Pass 1: d3 irreps 0,1 -> yh[12..29]; window f4[3..7] (floats 12..31) --
        {
            #pragma unroll
            for (int j = 12; j < 30; ++j) yh[j] = 0.0f;
            const float4* xc = xrow0 + 3;
            const float4* kc = khp + 3;
            float4 XA[5], KA[5], XB[5], KB[5];
            #pragma unroll
            for (int k = 0; k < 5; ++k) { KA[k] = kc[k]; XA[k] = xc[k]; }
            for (int c2 = 0; c2 < 15; ++c2) {
                #pragma unroll
                for (int k = 0; k < 5; ++k) { KB[k] = kc[12 + k]; XB[k] = xc[13 + k]; }
                D3PAIR(XA, KA, 0, 9, 12, 21);          // c even
                kc += 24; xc += 26;
                #pragma unroll
                for (int k = 0; k < 5; ++k) { KA[k] = kc[k]; XA[k] = xc[k]; }
                D3PAIR(XB, KB, 0, 9, 12, 21);          // c odd
            }
            // tail: c=30 already in A; load c=31 into B
            #pragma unroll
            for (int k = 0; k < 5; ++k) { KB[k] = kc[12 + k]; XB[k] = xc[13 + k]; }
            D3PAIR(XA, KA, 0, 9, 12, 21);
            D3PAIR(XB, KB, 0, 9, 12, 21);
        }

        // -- Pass 2: d3 irreps 2,3 -> yh[30..47]; window f4[7..11] (floats 28..47) --
        // irrep2 at float 30 -> window offset 2; irrep3 at float 39 -> offset 11
        {
            #pragma unroll
            for (int j = 30; j < 48; ++j) yh[j] = 0.0f;
            const float4* xc = xrow0 + 7;
            const float4* kc = khp + 7;
            float4 XA[5], KA[5], XB[5], KB[5];
            #pragma unroll
            for (int k = 0; k < 5; ++k) { KA[k] = kc[k]; XA[k] = xc[k]; }
            for (int c2 = 0; c2 < 15; ++c2) {
                #pragma unroll
                for (int k = 0; k < 5; ++k) { KB[k] = kc[12 + k]; XB[k] = xc[13 + k]; }
                D3PAIR(XA, KA, 2, 11, 30, 39);
                kc += 24; xc += 26;
                #pragma unroll
                for (int k = 0; k < 5; ++k) { KA[k] = kc[k]; XA[k] = xc[k]; }
                D3PAIR(XB, KB, 2, 11, 30, 39);
            }
            #pragma unroll
            for (int k = 0; k < 5; ++k) { KB[k] = kc[12 + k]; XB[k] = xc[13 + k]; }
            D3PAIR(XA, KA, 2, 11, 30, 39);
            D3PAIR(XB, KB, 2, 11, 30, 39);
        }

        // -- Pass 3: d1 + d2 irreps -> yh[0..11]; window f4[0..2] --
        {
            #pragma unroll
            for (int j = 0; j < 12; ++j) yh[j] = 0.0f;
            const float4* xc = xrow0;
            const float4* kc = khp;
            float4 XA[3], KA[3], XB[3], KB[3];
            #pragma unroll
            for (int k = 0; k < 3; ++k) { KA[k] = kc[k]; XA[k] = xc[k]; }
            for (int c2 = 0; c2 < 15; ++c2) {
                #pragma unroll
                for (int k = 0; k < 3; ++k) { KB[k] = kc[12 + k]; XB[k] = xc[13 + k]; }
                D12FMA(XA, KA);
                kc += 24; xc += 26;
                #pragma unroll
                for (int k = 0; k < 3; ++k) { KA[k] = kc[k]; XA[k] = xc[k]; }
                D12FMA(XB, KB);
            }
            #pragma unroll
            for (int k = 0; k < 3; ++k) { KB[k] = kc[12 + k]; XB[k] = xc[13 + k]; }
            D12FMA(XA, KA);
            D12FMA(XB, KB);
        }

        // ---- Stage D: y[s] = sum_j yh[j] * invT[s][j] + bias[f] ----
        // loop-interchanged: 4 outputs at a time, live = yh[48] + a[4]
        const float bf = bias[f];
        float4* op = (float4*)(out + ((b0 + (long long)b) * 32 + f) * 48);
        for (int sc = 0; sc < 12; ++sc) {
            float a[4];
            #pragma unroll
            for (int u = 0; u < 4; ++u) {
                const float* ir = invT + (sc * 4 + u) * 48;   // uniform -> s_load
                float acc = bf;
                #pragma unroll
                for (int j = 0; j < 48; ++j) acc = fmaf(yh[j], ir[j], acc);
                a[u] = acc;
            }
            op[sc] = make_float4(a[0], a[1], a[2], a[3]);
        }
    }
}

extern "C" void kernel_launch(void* const* d_in, const int* in_sizes, int n_in,
                              void* d_out, int out_size, void* d_ws, size_t ws_size,
                              hipStream_t stream) {
    const float* x    = (const float*)d_in[0];
    const float* kern = (const float*)d_in[1];
    const float* bias = (const float*)d_in[2];
    const float* d1   = (const float*)d_in[3];
    const float* d2   = (const float*)d_in[4];
    const float* d3   = (const float*)d_in[5];
    float* out = (float*)d_out;

    float* fwdT = (float*)d_ws;          // 2304 floats
    float* invT = fwdT + 2304;           // 2304 floats
    float* kh   = invT + 2304;           // 49152 floats

    prep_ft<<<9, 256, 0, stream>>>(d1, d2, d3, fwdT, invT);
    prep_kh<<<16, 256, 0, stream>>>(kern, fwdT, kh);
    fused_main<<<32768 / 8, 256, 0, stream>>>(x, fwdT, invT, kh, bias, out);
}